// Round 1
// baseline (9573.643 us; speedup 1.0000x reference)
//
#include <hip/hip_runtime.h>

// LightGCN: 3x item-item SpMM (with att scale) -> layer mean -> user-item SpMM
// -> batched pair dot.  M=100000 items, U=50000 users, D=64, B=4096.

#define MM 100000
#define UU 50000
#define DD 64

// COO SpMM: y[src] += val * x[dst], 16 lanes per edge, 4 dims per lane (float4).
__global__ void spmm_kernel(const int* __restrict__ src, const int* __restrict__ dst,
                            const float* __restrict__ val, const float* __restrict__ x,
                            float* __restrict__ y, int nnz,
                            const float* __restrict__ att, int layer) {
    long long t = (long long)blockIdx.x * blockDim.x + threadIdx.x;
    int e = (int)(t >> 4);
    if (e >= nnz) return;
    int q = ((int)t & 15) << 2;              // dim offset 0..60
    float scale = att ? att[layer] : 1.0f;   // att lives in device mem (parameter)
    int s = src[e];
    int d = dst[e];
    float v = val[e] * scale;
    const float4 xv = *reinterpret_cast<const float4*>(x + (size_t)d * DD + q);
    float* yp = y + (size_t)s * DD + q;
    // HW fp32 atomic (global_atomic_add_f32); plain atomicAdd may CAS-loop.
    unsafeAtomicAdd(yp + 0, v * xv.x);
    unsafeAtomicAdd(yp + 1, v * xv.y);
    unsafeAtomicAdd(yp + 2, v * xv.z);
    unsafeAtomicAdd(yp + 3, v * xv.w);
}

// o = a + b, float4-vectorized
__global__ void vec_add_kernel(const float4* __restrict__ a, const float4* __restrict__ b,
                               float4* __restrict__ o, int n4) {
    int i = blockIdx.x * blockDim.x + threadIdx.x;
    if (i >= n4) return;
    float4 x = a[i], y = b[i];
    o[i] = make_float4(x.x + y.x, x.y + y.y, x.z + y.z, x.w + y.w);
}

// gamma[b] = (1/16) * dot(uacc[users[b]], acc[items[b]]) ; one wave per pair
__global__ void batch_dot_kernel(const int* __restrict__ users, const int* __restrict__ items,
                                 const float* __restrict__ uacc, const float* __restrict__ acc,
                                 float* __restrict__ out, int B) {
    int t = blockIdx.x * blockDim.x + threadIdx.x;
    int b = t >> 6;
    int lane = t & 63;
    if (b >= B) return;
    int u = users[b];
    int it = items[b];
    float p = uacc[(size_t)u * DD + lane] * acc[(size_t)it * DD + lane];
    #pragma unroll
    for (int m = 32; m >= 1; m >>= 1) p += __shfl_xor(p, m, 64);
    if (lane == 0) out[b] = p * 0.0625f;   // (1/4 mean)^2 folded here
}

extern "C" void kernel_launch(void* const* d_in, const int* in_sizes, int n_in,
                              void* d_out, int out_size, void* d_ws, size_t ws_size,
                              hipStream_t stream) {
    const int*   users    = (const int*)d_in[0];
    const int*   items    = (const int*)d_in[1];
    const int*   ii_src   = (const int*)d_in[2];
    const int*   ii_dst   = (const int*)d_in[3];
    const float* ii_val   = (const float*)d_in[4];
    const int*   ui_src   = (const int*)d_in[5];
    const int*   ui_dst   = (const int*)d_in[6];
    const float* ui_val   = (const float*)d_in[7];
    const float* item_emb = (const float*)d_in[8];
    const float* att      = (const float*)d_in[9];

    const int E_ii = in_sizes[2];
    const int E_ui = in_sizes[5];
    const int B    = in_sizes[0];

    const size_t md = (size_t)MM * DD;           // 6.4M floats
    const size_t ud = (size_t)UU * DD;           // 3.2M floats
    float* buf0 = (float*)d_ws;                  // [M*D]
    float* buf1 = buf0 + md;                     // [M*D]
    float* acc  = buf1 + md;                     // [M*D] running sum of embs
    float* uacc = acc  + md;                     // [U*D]

    const int TB = 256;
    const int spmm_ii_blocks = (int)(((long long)E_ii * 16 + TB - 1) / TB);
    const int spmm_ui_blocks = (int)(((long long)E_ui * 16 + TB - 1) / TB);
    const int n4   = (int)(md / 4);
    const int add_blocks = (n4 + TB - 1) / TB;

    // layer 1: buf0 = spmm(item_emb) * att[0]
    hipMemsetAsync(buf0, 0, md * sizeof(float), stream);
    spmm_kernel<<<spmm_ii_blocks, TB, 0, stream>>>(ii_src, ii_dst, ii_val, item_emb, buf0, E_ii, att, 0);
    // acc = e0 + e1
    vec_add_kernel<<<add_blocks, TB, 0, stream>>>((const float4*)item_emb, (const float4*)buf0,
                                                  (float4*)acc, n4);
    // layer 2: buf1 = spmm(buf0) * att[1]
    hipMemsetAsync(buf1, 0, md * sizeof(float), stream);
    spmm_kernel<<<spmm_ii_blocks, TB, 0, stream>>>(ii_src, ii_dst, ii_val, buf0, buf1, E_ii, att, 1);
    vec_add_kernel<<<add_blocks, TB, 0, stream>>>((const float4*)acc, (const float4*)buf1,
                                                  (float4*)acc, n4);
    // layer 3: buf0 = spmm(buf1) * att[2]
    hipMemsetAsync(buf0, 0, md * sizeof(float), stream);
    spmm_kernel<<<spmm_ii_blocks, TB, 0, stream>>>(ii_src, ii_dst, ii_val, buf1, buf0, E_ii, att, 2);
    vec_add_kernel<<<add_blocks, TB, 0, stream>>>((const float4*)acc, (const float4*)buf0,
                                                  (float4*)acc, n4);

    // user aggregation on the un-normalized sum: uacc = spmm_ui(acc)
    hipMemsetAsync(uacc, 0, ud * sizeof(float), stream);
    spmm_kernel<<<spmm_ui_blocks, TB, 0, stream>>>(ui_src, ui_dst, ui_val, acc, uacc, E_ui, nullptr, 0);

    // gamma = (uacc/4) . (acc/4)
    const int dot_blocks = (B * 64 + TB - 1) / TB;
    batch_dot_kernel<<<dot_blocks, TB, 0, stream>>>(users, items, uacc, acc, (float*)d_out, B);
}

// Round 2
// 1439.033 us; speedup vs baseline: 6.6528x; 6.6528x over previous
//
#include <hip/hip_runtime.h>

// LightGCN on MI355X. Strategy: COO -> CSR counting sort each call (no atomics
// in the hot SpMMs), then gather-based SpMM: one wave per row, lane = dim,
// edge (dst,val) broadcast via shfl, register accumulate, one coalesced store.
// Round-1 evidence: atomic-scatter SpMM wrote 3.2 GB/dispatch to HBM (1 KB per
// edge, write-through + line amplification) -> 2.7 ms each. Gather writes 256 B
// per row instead.

#define MM 100000
#define UU 50000
#define DD 64

__global__ void hist_kernel(const int* __restrict__ src, int* __restrict__ counts, int nnz) {
    int i = blockIdx.x * blockDim.x + threadIdx.x;
    if (i < nnz) atomicAdd(&counts[src[i]], 1);
}

// Single-block exclusive scan (n <= ~400k fine). counts_cursor is read, then
// overwritten in-place with the exclusive prefix (serves as scatter cursor).
// row_ptr[0..n] gets the exclusive prefix + total.
__global__ void scan_kernel(int* __restrict__ counts_cursor, int* __restrict__ row_ptr, int n) {
    __shared__ int wave_sums[16];
    __shared__ int carry_sh;
    const int tid = threadIdx.x;
    const int lane = tid & 63, wid = tid >> 6;
    if (tid == 0) carry_sh = 0;
    __syncthreads();
    for (int base = 0; base < n; base += 4096) {
        int v[4];
        int s = 0;
        int idx0 = base + tid * 4;
        #pragma unroll
        for (int k = 0; k < 4; k++) {
            int i = idx0 + k;
            v[k] = (i < n) ? counts_cursor[i] : 0;
            s += v[k];
        }
        // wave-inclusive scan of per-thread sums
        int incl = s;
        #pragma unroll
        for (int m = 1; m < 64; m <<= 1) {
            int t = __shfl_up(incl, m, 64);
            if (lane >= m) incl += t;
        }
        if (lane == 63) wave_sums[wid] = incl;
        __syncthreads();
        int wave_off = 0;
        for (int w = 0; w < wid; w++) wave_off += wave_sums[w];
        int excl = carry_sh + wave_off + (incl - s);   // exclusive prefix for this thread's 4
        int run = excl;
        #pragma unroll
        for (int k = 0; k < 4; k++) {
            int i = idx0 + k;
            if (i < n) { row_ptr[i] = run; counts_cursor[i] = run; }
            run += v[k];
        }
        __syncthreads();                                // all reads of carry/wave_sums done
        if (tid == blockDim.x - 1) carry_sh = excl + s; // running total
        __syncthreads();
    }
    if (tid == 0) row_ptr[n] = carry_sh;
}

__global__ void scatter_kernel(const int* __restrict__ src, const int* __restrict__ dst,
                               const float* __restrict__ val, int* __restrict__ cursor,
                               int2* __restrict__ edges, int nnz) {
    int i = blockIdx.x * blockDim.x + threadIdx.x;
    if (i >= nnz) return;
    int s = src[i];
    int pos = atomicAdd(&cursor[s], 1);
    edges[pos] = make_int2(dst[i], __float_as_int(val[i]));
}

// Gather SpMM: one wave per row, lane = dim (D=64). y[r] = scale * sum_e val*x[dst].
// Optionally also acc[r] += result (fuses the layer-mean accumulation).
template <bool WRITE_Y, bool FUSE_ACC, bool SCALE>
__global__ void spmm_csr_kernel(const int* __restrict__ row_ptr, const int2* __restrict__ edges,
                                const float* __restrict__ x, float* __restrict__ y,
                                float* __restrict__ acc, const float* __restrict__ att,
                                int layer, int n_rows) {
    int w = (blockIdx.x * blockDim.x + threadIdx.x) >> 6;
    int lane = threadIdx.x & 63;
    if (w >= n_rows) return;
    int beg = row_ptr[w], end = row_ptr[w + 1];
    float sum = 0.f;
    for (int e = beg; e < end; e += 64) {
        int idx = e + lane;
        int2 ev = (idx < end) ? edges[idx] : make_int2(0, 0);  // coalesced 8B/lane
        int cnt = min(64, end - e);
        for (int j = 0; j < cnt; j++) {
            int d = __shfl(ev.x, j, 64);
            float v = __int_as_float(__shfl(ev.y, j, 64));
            sum = fmaf(v, x[(size_t)d * DD + lane], sum);      // 256B coalesced gather
        }
    }
    if (SCALE) sum *= att[layer];
    size_t o = (size_t)w * DD + lane;
    if (WRITE_Y) y[o] = sum;
    if (FUSE_ACC) acc[o] += sum;
}

// gamma[b] = (1/16) * dot(uacc[users[b]], acc[items[b]]) ; one wave per pair
__global__ void batch_dot_kernel(const int* __restrict__ users, const int* __restrict__ items,
                                 const float* __restrict__ uacc, const float* __restrict__ acc,
                                 float* __restrict__ out, int B) {
    int t = blockIdx.x * blockDim.x + threadIdx.x;
    int b = t >> 6;
    int lane = t & 63;
    if (b >= B) return;
    float p = uacc[(size_t)users[b] * DD + lane] * acc[(size_t)items[b] * DD + lane];
    #pragma unroll
    for (int m = 32; m >= 1; m >>= 1) p += __shfl_xor(p, m, 64);
    if (lane == 0) out[b] = p * 0.0625f;   // (1/4 mean) on each side folded here
}

extern "C" void kernel_launch(void* const* d_in, const int* in_sizes, int n_in,
                              void* d_out, int out_size, void* d_ws, size_t ws_size,
                              hipStream_t stream) {
    const int*   users    = (const int*)d_in[0];
    const int*   items    = (const int*)d_in[1];
    const int*   ii_src   = (const int*)d_in[2];
    const int*   ii_dst   = (const int*)d_in[3];
    const float* ii_val   = (const float*)d_in[4];
    const int*   ui_src   = (const int*)d_in[5];
    const int*   ui_dst   = (const int*)d_in[6];
    const float* ui_val   = (const float*)d_in[7];
    const float* item_emb = (const float*)d_in[8];
    const float* att      = (const float*)d_in[9];

    const int E_ii = in_sizes[2];
    const int E_ui = in_sizes[5];
    const int B    = in_sizes[0];

    const size_t md = (size_t)MM * DD;          // 6.4M floats = 25.6 MB
    float* buf0 = (float*)d_ws;                 // [M*D]
    float* buf1 = buf0 + md;                    // [M*D]
    float* acc  = buf1 + md;                    // [M*D] running sum e0+e1+e2+e3
    float* regE = acc + md;                     // 25.6 MB overlay region:
    int2*  ii_edges = (int2*)regE;              //   II phase: 3.2M int2 (25.6 MB)
    int2*  ui_edges = (int2*)regE;              //   UI phase: 1.6M int2 (12.8 MB) ...
    float* uacc = regE + 3200000;               //   ... + uacc [U*D] (12.8 MB)
    int* rp      = (int*)(regE + md);           // row_ptr, up to MM+1 ints
    int* cnt_cur = rp + (MM + 2);               // counts -> cursor, up to MM ints

    const int TB = 256;
    const int rows_per_blk = TB / 64;

    // ---- build item-item CSR (counting sort) ----
    hipMemsetAsync(cnt_cur, 0, MM * sizeof(int), stream);
    hist_kernel<<<(E_ii + TB - 1) / TB, TB, 0, stream>>>(ii_src, cnt_cur, E_ii);
    scan_kernel<<<1, 1024, 0, stream>>>(cnt_cur, rp, MM);
    scatter_kernel<<<(E_ii + TB - 1) / TB, TB, 0, stream>>>(ii_src, ii_dst, ii_val, cnt_cur, ii_edges, E_ii);

    // acc = e0
    hipMemcpyAsync(acc, item_emb, md * sizeof(float), hipMemcpyDeviceToDevice, stream);

    // ---- 3 propagation layers, acc-fused; layer 3 writes only acc ----
    const int ii_blocks = (MM + rows_per_blk - 1) / rows_per_blk;
    spmm_csr_kernel<true,  true, true><<<ii_blocks, TB, 0, stream>>>(rp, ii_edges, item_emb, buf0, acc, att, 0, MM);
    spmm_csr_kernel<true,  true, true><<<ii_blocks, TB, 0, stream>>>(rp, ii_edges, buf0,     buf1, acc, att, 1, MM);
    spmm_csr_kernel<false, true, true><<<ii_blocks, TB, 0, stream>>>(rp, ii_edges, buf1, (float*)nullptr, acc, att, 2, MM);

    // ---- build user-item CSR (overlays the II edge region; II edges no longer needed) ----
    hipMemsetAsync(cnt_cur, 0, UU * sizeof(int), stream);
    hist_kernel<<<(E_ui + TB - 1) / TB, TB, 0, stream>>>(ui_src, cnt_cur, E_ui);
    scan_kernel<<<1, 1024, 0, stream>>>(cnt_cur, rp, UU);
    scatter_kernel<<<(E_ui + TB - 1) / TB, TB, 0, stream>>>(ui_src, ui_dst, ui_val, cnt_cur, ui_edges, E_ui);

    // uacc = spmm_ui(acc)   (scales folded into final dot)
    const int ui_blocks = (UU + rows_per_blk - 1) / rows_per_blk;
    spmm_csr_kernel<true, false, false><<<ui_blocks, TB, 0, stream>>>(rp, ui_edges, acc, uacc, (float*)nullptr, att, 0, UU);

    // gamma = (uacc/4) . (acc/4)
    batch_dot_kernel<<<(B * 64 + TB - 1) / TB, TB, 0, stream>>>(users, items, uacc, acc, (float*)d_out, B);
}